// Round 1
// 1395.337 us; speedup vs baseline: 1.1015x; 1.1015x over previous
//
#include <hip/hip_runtime.h>
#include <cstdint>
#include <cstddef>

// ---------------------------------------------------------------------------
// SCM_MLP: 4 layers of  out = relu(out @ (W*mask)^T + exp(mu + sigma*z))
// B = H = 4096, L = 4.  Output: concat of per-layer activations [B, L*H] fp32.
//
// R4: replace the 2-phase 128x128 loop (539 TF, MfmaUtil 22.5%) with the
// verified 256x256 / BK=64 / 8-wave 8-phase counted-vmcnt template (T3+T4),
// + st_16x32 LDS XOR swizzle (T2) + setprio around MFMA clusters (T5) +
// bijective XCD block swizzle (T1).  Grid = 256 blocks = 1/CU, 128 KiB LDS.
// Head conversions folded into one grid-stride prep kernel (launch count 5).
// Keeps: fused noise+relu epilogue, fused next-layer W*mask->bf16 conversion.
// ---------------------------------------------------------------------------

typedef __bf16 bf16x8 __attribute__((ext_vector_type(8)));
typedef float  f32x4  __attribute__((ext_vector_type(4)));

constexpr int HDIM = 4096;
constexpr int BDIM = 4096;
constexpr int LDIM = 4;
constexpr int OUTSTRIDE = LDIM * HDIM;
constexpr int NKT = HDIM / 64;          // 64 K-tiles of 64

__device__ __forceinline__ unsigned short f2bf(float f) {
    union { float f; unsigned int u; } v; v.f = f;
    unsigned int u = v.u;
    return (unsigned short)((u + 0x7FFFu + ((u >> 16) & 1u)) >> 16);  // RNE
}

#define GLD16(gp, lp)                                                        \
    __builtin_amdgcn_global_load_lds(                                        \
        (__attribute__((address_space(1))) void*)(uintptr_t)(const void*)(gp), \
        (__attribute__((address_space(3))) void*)(unsigned int)(uintptr_t)(void*)(lp), \
        16, 0, 0)

// raw barrier (no vmcnt drain!) with IR-level memory fences to pin code motion
#define BARRIER do { asm volatile("" ::: "memory");                          \
                     __builtin_amdgcn_s_barrier();                           \
                     asm volatile("" ::: "memory"); } while (0)
#define LGKM0    asm volatile("s_waitcnt lgkmcnt(0)" ::: "memory")
#define VMCNT(n) asm volatile("s_waitcnt vmcnt(" #n ")" ::: "memory")

// ---------------------------------------------------------------------------
// prep: x -> bf16 activations, and layer-0 W*mask -> bf16, one kernel.
// ---------------------------------------------------------------------------
__global__ void prep_kernel(const float* __restrict__ x,
                            const float* __restrict__ w,
                            const float* __restrict__ m,
                            unsigned short* __restrict__ actOut,
                            unsigned short* __restrict__ wOut) {
    const size_t stride = (size_t)gridDim.x * blockDim.x;
    const size_t n4 = (size_t)BDIM * HDIM / 4;
    for (size_t i = (size_t)blockIdx.x * blockDim.x + threadIdx.x; i < n4; i += stride) {
        const float4 v = reinterpret_cast<const float4*>(x)[i];
        ushort4 r;
        r.x = f2bf(v.x); r.y = f2bf(v.y); r.z = f2bf(v.z); r.w = f2bf(v.w);
        reinterpret_cast<ushort4*>(actOut)[i] = r;
        const float4 wv = reinterpret_cast<const float4*>(w)[i];
        const float4 mv = reinterpret_cast<const float4*>(m)[i];
        ushort4 rw;
        rw.x = f2bf(wv.x * mv.x); rw.y = f2bf(wv.y * mv.y);
        rw.z = f2bf(wv.z * mv.z); rw.w = f2bf(wv.w * mv.w);
        reinterpret_cast<ushort4*>(wOut)[i] = rw;
    }
}

// fallback (only used if workspace too small to double-buffer weights)
__global__ void cvt_w_kernel(const float* __restrict__ w,
                             const float* __restrict__ m,
                             unsigned short* __restrict__ o) {
    size_t i = ((size_t)blockIdx.x * blockDim.x + threadIdx.x) * 4;
    const float4 wv = *reinterpret_cast<const float4*>(w + i);
    const float4 mv = *reinterpret_cast<const float4*>(m + i);
    ushort4 r;
    r.x = f2bf(wv.x * mv.x); r.y = f2bf(wv.y * mv.y);
    r.z = f2bf(wv.z * mv.z); r.w = f2bf(wv.w * mv.w);
    *reinterpret_cast<ushort4*>(o + i) = r;
}

// ---------------------------------------------------------------------------
// 256x256 tile, BK=64, 512 threads = 8 waves (2M x 4N), wave tile 128x64.
// LDS: sA/sW[buf][half][128x64 bf16] = 128 KiB total (2 K-tile buffers).
// Each half staged as 16 x (16rows x 32cols) 1024B subtiles, st_16x32-swizzled
// via pre-swizzled global source (GLD dest must stay linear).
// 8 phases / 2 K-tiles; counted vmcnt(4) only at phases 4 and 8.
// ---------------------------------------------------------------------------
__global__ __launch_bounds__(512, 2) void gemm_layer(
    const unsigned short* __restrict__ A,    // [BDIM, HDIM] bf16
    const unsigned short* __restrict__ W,    // [HDIM, HDIM] bf16 (masked)
    const float* __restrict__ mu,            // [HDIM]
    const float* __restrict__ sg,            // [HDIM]
    const float* __restrict__ z,             // [BDIM, HDIM] fp32
    float* __restrict__ out,                 // [BDIM, OUTSTRIDE] fp32
    int outCol0,
    unsigned short* __restrict__ actOut,     // bf16 next-layer input or null
    const float* __restrict__ wNextF,        // next layer W fp32 or null
    const float* __restrict__ mNextF,        // next layer mask fp32 or null
    unsigned short* __restrict__ wNextOut)   // next layer bf16 out or null
{
    __shared__ unsigned short sA[2][2][8192];   // [buf][half][128*64]
    __shared__ unsigned short sW[2][2][8192];

    const int tid   = threadIdx.x;
    const int wave  = tid >> 6;      // 0..7
    const int lane  = tid & 63;
    const int quad  = lane >> 4;
    const int l16   = lane & 15;
    const int wm    = wave >> 2;     // 0..1  (M half)
    const int wn    = wave & 3;      // 0..3  (N quarter)
    const int whalf = wn >> 1;       // which W half
    const int wq8   = (wn & 1) << 3; // subtile base within W half

    // bijective XCD swizzle: 256 blocks, 32 consecutive per XCD
    int flat = blockIdx.y * gridDim.x + blockIdx.x;          // 0..255
    flat = ((flat & 7) << 5) | (flat >> 3);
    const int bm0 = (flat >> 4) << 8;
    const int bn0 = (flat & 15) << 8;

    // ---- staging addressing: wave w stages subtiles 2w, 2w+1 of each half.
    // subtile c=(2w+j): fragRow=w, ks=j.  lane l -> row w*16+(l>>2),
    // col chunk pre-swizzled: ((l&3)^((l>>4)&2))  (st_16x32 inverse on source)
    const int srow = (wave << 4) + (lane >> 2);
    const int scc  = (((lane & 3) ^ ((lane >> 4) & 2)) << 3);
    const unsigned short* gA0 = A + (size_t)(bm0 + srow) * HDIM + scc;
    const unsigned short* gA1 = gA0 + (size_t)128 * HDIM;
    const unsigned short* gW0 = W + (size_t)(bn0 + srow) * HDIM + scc;
    const unsigned short* gW1 = gW0 + (size_t)128 * HDIM;
    const int ldst = wave << 10;     // wave-uniform LDS elem base (2 subtiles)

#define STAGE(dstp, gp, kt) do {                                     \
        GLD16((gp) + ((kt) << 6),      (dstp) + ldst);               \
        GLD16((gp) + ((kt) << 6) + 32, (dstp) + ldst + 512);         \
    } while (0)

    // ---- fragment read: subtile s=(fragIdx*2+ks), elem off = swz(l16*64+quad*16)/2
    const int rby = (l16 << 6) + (quad << 4);
    const int rdE = (rby ^ (((rby >> 9) & 1) << 5)) >> 1;

    f32x4  acc[8][4] = {};
    bf16x8 a[4][2], b[2][2];

#define DSA(B, RH) do {                                                        \
        _Pragma("unroll") for (int t_ = 0; t_ < 4; ++t_)                       \
        _Pragma("unroll") for (int k_ = 0; k_ < 2; ++k_)                       \
            a[t_][k_] = *reinterpret_cast<const bf16x8*>(                      \
                &sA[B][wm][((((RH)*4 + t_) << 1) + k_) * 512 + rdE]);          \
    } while (0)

#define DSB(B, CH) do {                                                        \
        _Pragma("unroll") for (int u_ = 0; u_ < 2; ++u_)                       \
        _Pragma("unroll") for (int k_ = 0; k_ < 2; ++k_)                       \
            b[u_][k_] = *reinterpret_cast<const bf16x8*>(                      \
                &sW[B][whalf][(wq8 + (((CH)*2 + u_) << 1) + k_) * 512 + rdE]); \
    } while (0)

#define MM(RH, CH) do {                                                        \
        __builtin_amdgcn_s_setprio(1);                                         \
        _Pragma("unroll") for (int t_ = 0; t_ < 4; ++t_)                       \
        _Pragma("unroll") for (int u_ = 0; u_ < 2; ++u_)                       \
        _Pragma("unroll") for (int k_ = 0; k_ < 2; ++k_)                       \
            acc[(RH)*4 + t_][(CH)*2 + u_] =                                    \
                __builtin_amdgcn_mfma_f32_16x16x32_bf16(                       \
                    a[t_][k_], b[u_][k_], acc[(RH)*4 + t_][(CH)*2 + u_], 0,0,0); \
        __builtin_amdgcn_s_setprio(0);                                         \
    } while (0)

    // ---- prologue: tile0 fully + A halves of tile1; confirm tile0 landed
    STAGE(&sA[0][0][0], gA0, 0);
    STAGE(&sA[0][1][0], gA1, 0);
    STAGE(&sW[0][0][0], gW0, 0);
    STAGE(&sW[0][1][0], gW1, 0);
    STAGE(&sA[1][0][0], gA0, 1);
    STAGE(&sA[1][1][0], gA1, 1);
    VMCNT(4);                                   // tile0 landed; A(1) may fly
    BARRIER;

    // ---- main loop: 2 K-tiles / iteration, 8 phases ----
    for (int it = 0; it < NKT / 2; ++it) {
        const int E = it << 1;                  // even tile -> buf0, odd -> buf1
        // P1: ds A-front + Wc01 (buf0); stage W0(E+1)->buf1
        DSA(0, 0); DSB(0, 0);
        STAGE(&sW[1][0][0], gW0, E + 1);
        BARRIER; LGKM0; MM(0, 0); BARRIER;
        // P2: ds Wc23 (buf0); stage W1(E+1)->buf1
        DSB(0, 1);
        STAGE(&sW[1][1][0], gW1, E + 1);
        BARRIER; LGKM0; MM(0, 1); BARRIER;
        // P3: ds A-back (buf0)
        DSA(0, 1);
        BARRIER; LGKM0; MM(1, 1); BARRIER;
        // P4: ds Wc01 (buf0); stage A halves (E+2)->buf0 (A(E) free after P3)
        DSB(0, 0);
        if (E + 2 < NKT) {
            STAGE(&sA[0][0][0], gA0, E + 2);
            STAGE(&sA[0][1][0], gA1, E + 2);
            VMCNT(4);                           // tile E+1 fully landed
        } else {
            VMCNT(0);                           // tail: drain (skips change order)
        }
        BARRIER; LGKM0; MM(1, 0); BARRIER;
        // P5: ds A-front + Wc01 (buf1); stage W0(E+2)->buf0 (W(E) free after P4)
        DSA(1, 0); DSB(1, 0);
        if (E + 2 < NKT) STAGE(&sW[0][0][0], gW0, E + 2);
        BARRIER; LGKM0; MM(0, 0); BARRIER;
        // P6: ds Wc23 (buf1); stage W1(E+2)->buf0
        DSB(1, 1);
        if (E + 2 < NKT) STAGE(&sW[0][1][0], gW1, E + 2);
        BARRIER; LGKM0; MM(0, 1); BARRIER;
        // P7: ds A-back (buf1)
        DSA(1, 1);
        BARRIER; LGKM0; MM(1, 1); BARRIER;
        // P8: ds Wc01 (buf1); stage A halves (E+3)->buf1 (A(E+1) free after P7)
        DSB(1, 0);
        if (E + 3 < NKT) {
            STAGE(&sA[1][0][0], gA0, E + 3);
            STAGE(&sA[1][1][0], gA1, E + 3);
            VMCNT(4);                           // tile E+2 fully landed
        } else {
            VMCNT(0);
        }
        BARRIER; LGKM0; MM(1, 0); BARRIER;
    }

#undef STAGE
#undef DSA
#undef DSB
#undef MM

    // ---- epilogue: + exp(mu + sigma*z), relu, store fp32 + bf16 ----
    float munv[4], sgnv[4];
    int   ncol[4];
#pragma unroll
    for (int u = 0; u < 4; ++u) {
        ncol[u] = bn0 + (wn << 6) + (u << 4) + l16;
        munv[u] = mu[ncol[u]];
        sgnv[u] = sg[ncol[u]];
    }

#pragma unroll
    for (int t = 0; t < 8; ++t) {
#pragma unroll
        for (int r = 0; r < 4; ++r) {
            const int mrow = bm0 + (wm << 7) + (t << 4) + (quad << 2) + r;
            const float* zr = z + (size_t)mrow * HDIM;
            float* orow = out + (size_t)mrow * OUTSTRIDE + outCol0;
            unsigned short* arow = actOut ? actOut + (size_t)mrow * HDIM : nullptr;
#pragma unroll
            for (int u = 0; u < 4; ++u) {
                float v = acc[t][u][r] + __expf(fmaf(sgnv[u], zr[ncol[u]], munv[u]));
                v = fmaxf(v, 0.0f);
                orow[ncol[u]] = v;
                if (actOut) arow[ncol[u]] = f2bf(v);
            }
        }
    }

    // ---- fused conversion of next layer's weights (W*mask -> bf16) ----
    // 256 blocks cover 4096x4096 = 16.78M elems -> 65536/block, 128/thread.
    if (wNextF) {
        const size_t base = ((size_t)(blockIdx.y * gridDim.x + blockIdx.x) * 65536)
                          + (size_t)tid * 4;
#pragma unroll
        for (int j = 0; j < 32; ++j) {
            const size_t i = base + (size_t)j * 2048;   // 512 thr * 4 elems
            const float4 wv = *reinterpret_cast<const float4*>(wNextF + i);
            const float4 mv = *reinterpret_cast<const float4*>(mNextF + i);
            ushort4 rr;
            rr.x = f2bf(wv.x * mv.x); rr.y = f2bf(wv.y * mv.y);
            rr.z = f2bf(wv.z * mv.z); rr.w = f2bf(wv.w * mv.w);
            *reinterpret_cast<ushort4*>(wNextOut + i) = rr;
        }
    }
}

// ---------------------------------------------------------------------------
extern "C" void kernel_launch(void* const* d_in, const int* in_sizes, int n_in,
                              void* d_out, int out_size, void* d_ws, size_t ws_size,
                              hipStream_t stream) {
    const float* x       = (const float*)d_in[0];
    const float* weights = (const float*)d_in[1];
    const float* masks   = (const float*)d_in[2];
    const float* mu      = (const float*)d_in[3];
    const float* sigma   = (const float*)d_in[4];
    const float* z       = (const float*)d_in[5];
    float* out = (float*)d_out;

    const size_t NELEM = (size_t)BDIM * HDIM;           // 16.78M
    unsigned short* actA = (unsigned short*)d_ws;
    unsigned short* actB = actA + NELEM;
    unsigned short* wbA  = actB + NELEM;
    unsigned short* wbB  = wbA + NELEM;                 // needs 128 MB total

    const bool fuse = ws_size >= 4 * NELEM * sizeof(unsigned short);
    const int CVT_BLOCKS = (int)(NELEM / 4) / 256;      // 16384 (fallback only)

    // one prep kernel: x->bf16 and W0*mask0->bf16
    prep_kernel<<<2048, 256, 0, stream>>>(x, weights, masks, actA, wbA);

    unsigned short* cur = actA;
    unsigned short* nxt = actB;
    unsigned short* wCur = wbA;
    unsigned short* wNxt = fuse ? wbB : wbA;

    dim3 grid(HDIM / 256, BDIM / 256);   // (16, 16) = 256 blocks = 1/CU

    for (int l = 0; l < LDIM; ++l) {
        if (!fuse && l > 0) {
            cvt_w_kernel<<<CVT_BLOCKS, 256, 0, stream>>>(
                weights + (size_t)l * NELEM, masks + (size_t)l * NELEM, wCur);
        }
        const bool doNext = fuse && (l + 1 < LDIM);
        gemm_layer<<<grid, 512, 0, stream>>>(
            cur, wCur,
            mu + (size_t)l * HDIM, sigma + (size_t)l * HDIM,
            z + (size_t)l * NELEM,
            out, l * HDIM,
            (l == LDIM - 1) ? nullptr : nxt,
            doNext ? weights + (size_t)(l + 1) * NELEM : nullptr,
            doNext ? masks + (size_t)(l + 1) * NELEM : nullptr,
            doNext ? wNxt : nullptr);

        unsigned short* tmp = cur; cur = nxt; nxt = tmp;
        if (fuse) { unsigned short* tw = wCur; wCur = wNxt; wNxt = tw; }
    }
}

// Round 2
// 1251.358 us; speedup vs baseline: 1.2283x; 1.1151x over previous
//
#include <hip/hip_runtime.h>
#include <cstdint>
#include <cstddef>

// ---------------------------------------------------------------------------
// SCM_MLP: 4 layers of  out = relu(out @ (W*mask)^T + exp(mu + sigma*z))
// B = H = 4096, L = 4.  Output: concat of per-layer activations [B, L*H] fp32.
//
// R5: core (8-phase counted-vmcnt 256x256) confirmed at ~62% MfmaUtil; the
// dispatch-average 25% was the serial memory tail.  This round:
//  (a) next-layer W*mask->bf16 cvt interleaved INTO the K-loop (1 chunk/iter,
//      loads at P3 drained by P4's vmcnt(4), store after it) -> tail -160MB.
//  (b) epilogue via LDS transpose: acc -> LDS (per-wave 16KB slice, XOR swz),
//      read back row-contiguous -> float4 z loads, float4 out stores, ushort4
//      actOut stores (was scalar 4B/2B).
//  (c) MM loop k-outermost: dependent same-acc MFMAs spaced 8 apart.
// ---------------------------------------------------------------------------

typedef __bf16 bf16x8 __attribute__((ext_vector_type(8)));
typedef float  f32x4  __attribute__((ext_vector_type(4)));

constexpr int HDIM = 4096;
constexpr int BDIM = 4096;
constexpr int LDIM = 4;
constexpr int OUTSTRIDE = LDIM * HDIM;
constexpr int NKT = HDIM / 64;          // 64 K-tiles of 64
static_assert(NKT / 2 == 32, "cvt interleave assumes 32 main-loop iterations");

__device__ __forceinline__ unsigned short f2bf(float f) {
    union { float f; unsigned int u; } v; v.f = f;
    unsigned int u = v.u;
    return (unsigned short)((u + 0x7FFFu + ((u >> 16) & 1u)) >> 16);  // RNE
}

#define GLD16(gp, lp)                                                        \
    __builtin_amdgcn_global_load_lds(                                        \
        (__attribute__((address_space(1))) void*)(uintptr_t)(const void*)(gp), \
        (__attribute__((address_space(3))) void*)(unsigned int)(uintptr_t)(void*)(lp), \
        16, 0, 0)

// raw barrier (no vmcnt drain!) with IR-level memory fences to pin code motion
#define BARRIER do { asm volatile("" ::: "memory");                          \
                     __builtin_amdgcn_s_barrier();                           \
                     asm volatile("" ::: "memory"); } while (0)
#define LGKM0    asm volatile("s_waitcnt lgkmcnt(0)" ::: "memory")
#define VMCNT(n) asm volatile("s_waitcnt vmcnt(" #n ")" ::: "memory")

// ---------------------------------------------------------------------------
// prep: x -> bf16 activations, and layer-0 W*mask -> bf16, one kernel.
// ---------------------------------------------------------------------------
__global__ void prep_kernel(const float* __restrict__ x,
                            const float* __restrict__ w,
                            const float* __restrict__ m,
                            unsigned short* __restrict__ actOut,
                            unsigned short* __restrict__ wOut) {
    const size_t stride = (size_t)gridDim.x * blockDim.x;
    const size_t n4 = (size_t)BDIM * HDIM / 4;
    for (size_t i = (size_t)blockIdx.x * blockDim.x + threadIdx.x; i < n4; i += stride) {
        const float4 v = reinterpret_cast<const float4*>(x)[i];
        ushort4 r;
        r.x = f2bf(v.x); r.y = f2bf(v.y); r.z = f2bf(v.z); r.w = f2bf(v.w);
        reinterpret_cast<ushort4*>(actOut)[i] = r;
        const float4 wv = reinterpret_cast<const float4*>(w)[i];
        const float4 mv = reinterpret_cast<const float4*>(m)[i];
        ushort4 rw;
        rw.x = f2bf(wv.x * mv.x); rw.y = f2bf(wv.y * mv.y);
        rw.z = f2bf(wv.z * mv.z); rw.w = f2bf(wv.w * mv.w);
        reinterpret_cast<ushort4*>(wOut)[i] = rw;
    }
}

// fallback (only used if workspace too small to double-buffer weights)
__global__ void cvt_w_kernel(const float* __restrict__ w,
                             const float* __restrict__ m,
                             unsigned short* __restrict__ o) {
    size_t i = ((size_t)blockIdx.x * blockDim.x + threadIdx.x) * 4;
    const float4 wv = *reinterpret_cast<const float4*>(w + i);
    const float4 mv = *reinterpret_cast<const float4*>(m + i);
    ushort4 r;
    r.x = f2bf(wv.x * mv.x); r.y = f2bf(wv.y * mv.y);
    r.z = f2bf(wv.z * mv.z); r.w = f2bf(wv.w * mv.w);
    *reinterpret_cast<ushort4*>(o + i) = r;
}

// ---------------------------------------------------------------------------
// 256x256 tile, BK=64, 512 threads = 8 waves (2M x 4N), wave tile 128x64.
// LDS: sAll[A/W][buf][half][128x64 bf16] = 128 KiB (2 K-tile buffers).
// 8 phases / 2 K-tiles; counted vmcnt(4) only at phases 4 and 8.
// ---------------------------------------------------------------------------
template <bool DO_CVT, bool DO_ACT>
__global__ __launch_bounds__(512, 2) void gemm_layer(
    const unsigned short* __restrict__ A,    // [BDIM, HDIM] bf16
    const unsigned short* __restrict__ W,    // [HDIM, HDIM] bf16 (masked)
    const float* __restrict__ mu,            // [HDIM]
    const float* __restrict__ sg,            // [HDIM]
    const float* __restrict__ z,             // [BDIM, HDIM] fp32
    float* __restrict__ out,                 // [BDIM, OUTSTRIDE] fp32
    int outCol0,
    unsigned short* __restrict__ actOut,     // bf16 next-layer input (DO_ACT)
    const float* __restrict__ wNextF,        // next layer W fp32 (DO_CVT)
    const float* __restrict__ mNextF,        // next layer mask fp32 (DO_CVT)
    unsigned short* __restrict__ wNextOut)   // next layer bf16 out (DO_CVT)
{
    __shared__ unsigned short sAll[2][2][2][8192];   // [A/W][buf][half][128*64]

    const int tid   = threadIdx.x;
    const int wave  = tid >> 6;      // 0..7
    const int lane  = tid & 63;
    const int quad  = lane >> 4;
    const int l16   = lane & 15;
    const int wm    = wave >> 2;     // 0..1  (M half)
    const int wn    = wave & 3;      // 0..3  (N quarter)
    const int whalf = wn >> 1;       // which W half
    const int wq8   = (wn & 1) << 3; // subtile base within W half

    // bijective XCD swizzle: 256 blocks, 32 consecutive tiles per XCD
    int flat = blockIdx.y * gridDim.x + blockIdx.x;          // 0..255
    flat = ((flat & 7) << 5) | (flat >> 3);
    const int bm0 = (flat >> 4) << 8;
    const int bn0 = (flat & 15) << 8;

    // ---- staging addressing (pre-swizzled source, linear LDS dest) ----
    const int srow = (wave << 4) + (lane >> 2);
    const int scc  = (((lane & 3) ^ ((lane >> 4) & 2)) << 3);
    const unsigned short* gA0 = A + (size_t)(bm0 + srow) * HDIM + scc;
    const unsigned short* gA1 = gA0 + (size_t)128 * HDIM;
    const unsigned short* gW0 = W + (size_t)(bn0 + srow) * HDIM + scc;
    const unsigned short* gW1 = gW0 + (size_t)128 * HDIM;
    const int ldst = wave << 10;     // wave-uniform LDS elem base (2 subtiles)

#define STAGE(dstp, gp, kt) do {                                     \
        GLD16((gp) + ((kt) << 6),      (dstp) + ldst);               \
        GLD16((gp) + ((kt) << 6) + 32, (dstp) + ldst + 512);         \
    } while (0)

    // ---- fragment read addressing ----
    const int rby = (l16 << 6) + (quad << 4);
    const int rdE = (rby ^ (((rby >> 9) & 1) << 5)) >> 1;

    f32x4  acc[8][4] = {};
    bf16x8 a[4][2], b[2][2];

#define DSA(B, RH) do {                                                        \
        _Pragma("unroll") for (int t_ = 0; t_ < 4; ++t_)                       \
        _Pragma("unroll") for (int k_ = 0; k_ < 2; ++k_)                       \
            a[t_][k_] = *reinterpret_cast<const bf16x8*>(                      \
                &sAll[0][B][wm][((((RH)*4 + t_) << 1) + k_) * 512 + rdE]);     \
    } while (0)

#define DSB(B, CH) do {                                                        \
        _Pragma("unroll") for (int u_ = 0; u_ < 2; ++u_)                       \
        _Pragma("unroll") for (int k_ = 0; k_ < 2; ++k_)                       \
            b[u_][k_] = *reinterpret_cast<const bf16x8*>(                      \
                &sAll[1][B][whalf][(wq8 + (((CH)*2 + u_) << 1) + k_) * 512 + rdE]); \
    } while (0)

// k_ OUTERMOST: same-acc dependent MFMAs spaced 8 apart
#define MM(RH, CH) do {                                                        \
        __builtin_amdgcn_s_setprio(1);                                         \
        _Pragma("unroll") for (int k_ = 0; k_ < 2; ++k_)                       \
        _Pragma("unroll") for (int t_ = 0; t_ < 4; ++t_)                       \
        _Pragma("unroll") for (int u_ = 0; u_ < 2; ++u_)                       \
            acc[(RH)*4 + t_][(CH)*2 + u_] =                                    \
                __builtin_amdgcn_mfma_f32_16x16x32_bf16(                       \
                    a[t_][k_], b[u_][k_], acc[(RH)*4 + t_][(CH)*2 + u_], 0,0,0); \
        __builtin_amdgcn_s_setprio(0);                                         \
    } while (0)

    // per-block cvt range: 65536 elems, one 4-elem chunk/thread/iteration
    const size_t cvtB = (size_t)(blockIdx.y * gridDim.x + blockIdx.x) * 65536
                      + (size_t)tid * 4;

    // ---- prologue: tile0 fully + A halves of tile1 ----
    STAGE(&sAll[0][0][0][0], gA0, 0);
    STAGE(&sAll[0][0][1][0], gA1, 0);
    STAGE(&sAll[1][0][0][0], gW0, 0);
    STAGE(&sAll[1][0][1][0], gW1, 0);
    STAGE(&sAll[0][1][0][0], gA0, 1);
    STAGE(&sAll[0][1][1][0], gA1, 1);
    VMCNT(4);                                   // tile0 landed; A(1) may fly
    BARRIER;

    // ---- main loop: 2 K-tiles / iteration, 8 phases ----
    for (int it = 0; it < NKT / 2; ++it) {
        const int E = it << 1;
        float4 cwv, cmv;
        size_t ci = 0;
        // P1: ds A-front + Wc01 (buf0); stage W0(E+1)->buf1
        DSA(0, 0); DSB(0, 0);
        STAGE(&sAll[1][1][0][0], gW0, E + 1);
        BARRIER; LGKM0; MM(0, 0); BARRIER;
        // P2: ds Wc23 (buf0); stage W1(E+1)->buf1
        DSB(0, 1);
        STAGE(&sAll[1][1][1][0], gW1, E + 1);
        BARRIER; LGKM0; MM(0, 1); BARRIER;
        // P3: ds A-back (buf0); issue cvt loads (drained by P4's vmcnt)
        DSA(0, 1);
        if constexpr (DO_CVT) {
            ci  = cvtB + (size_t)it * 2048;
            cwv = *reinterpret_cast<const float4*>(wNextF + ci);
            cmv = *reinterpret_cast<const float4*>(mNextF + ci);
        }
        BARRIER; LGKM0; MM(1, 1); BARRIER;
        // P4: ds Wc01 (buf0); stage A(E+2)->buf0; counted vmcnt; cvt store
        DSB(0, 0);
        if (E + 2 < NKT) {
            STAGE(&sAll[0][0][0][0], gA0, E + 2);
            STAGE(&sAll[0][0][1][0], gA1, E + 2);
            VMCNT(4);                           // tile E+1 fully landed (+cvt)
        } else {
            VMCNT(0);
        }
        if constexpr (DO_CVT) {
            ushort4 rr4;
            rr4.x = f2bf(cwv.x * cmv.x); rr4.y = f2bf(cwv.y * cmv.y);
            rr4.z = f2bf(cwv.z * cmv.z); rr4.w = f2bf(cwv.w * cmv.w);
            *reinterpret_cast<ushort4*>(wNextOut + ci) = rr4;
        }
        BARRIER; LGKM0; MM(1, 0); BARRIER;
        // P5: ds A-front + Wc01 (buf1); stage W0(E+2)->buf0
        DSA(1, 0); DSB(1, 0);
        if (E + 2 < NKT) STAGE(&sAll[1][0][0][0], gW0, E + 2);
        BARRIER; LGKM0; MM(0, 0); BARRIER;
        // P6: ds Wc23 (buf1); stage W1(E+2)->buf0
        DSB(1, 1);
        if (E + 2 < NKT) STAGE(&sAll[1][0][1][0], gW1, E + 2);
        BARRIER; LGKM0; MM(0, 1); BARRIER;
        // P7: ds A-back (buf1)
        DSA(1, 1);
        BARRIER; LGKM0; MM(1, 1); BARRIER;
        // P8: ds Wc01 (buf1); stage A(E+3)->buf1; counted vmcnt
        DSB(1, 0);
        if (E + 3 < NKT) {
            STAGE(&sAll[0][1][0][0], gA0, E + 3);
            STAGE(&sAll[0][1][1][0], gA1, E + 3);
            VMCNT(4);                           // tile E+2 fully landed (+store)
        } else {
            VMCNT(0);
        }
        BARRIER; LGKM0; MM(1, 0); BARRIER;
    }

#undef STAGE
#undef DSA
#undef DSB
#undef MM

    // ---- epilogue: LDS-transpose -> fully vectorized noise+relu+store ----
    // Each wave owns a 16KB slice (4096 floats = 64 rows x 64 cols), 2 halves.
    float* esl = reinterpret_cast<float*>(sAll) + (wave << 12);
    const int gcol = bn0 + (wn << 6) + (l16 << 2);       // 4 consecutive cols
    const float4 muv = *reinterpret_cast<const float4*>(mu + gcol);
    const float4 sgv = *reinterpret_cast<const float4*>(sg + gcol);

#pragma unroll
    for (int h = 0; h < 2; ++h) {
        // write phase: scatter acc fragments (XOR-swizzled on 16B chunks)
#pragma unroll
        for (int t4 = 0; t4 < 4; ++t4) {
#pragma unroll
            for (int r = 0; r < 4; ++r) {
                const int rowl = (t4 << 4) + (quad << 2) + r;
                const int sw = rowl & 7;
#pragma unroll
                for (int u = 0; u < 4; ++u) {
                    const int col4 = (u << 2) + (l16 >> 2);
                    esl[(rowl << 6) + ((col4 ^ sw) << 2) + (l16 & 3)] =
                        acc[h * 4 + t4][u][r];
                }
            }
        }
        LGKM0;   // writes visible before same-wave reads
        // read phase: 16 lanes x 4 rows per round, row-contiguous float4
#pragma unroll
        for (int rr = 0; rr < 16; ++rr) {
            const int rowl = (rr << 2) + quad;
            const int col4 = l16 ^ (rowl & 7);
            const f32x4 vv = *reinterpret_cast<const f32x4*>(
                &esl[(rowl << 6) + (col4 << 2)]);
            const int grow = bm0 + (wm << 7) + (h << 6) + rowl;
            const float4 zv = *reinterpret_cast<const float4*>(
                z + (size_t)grow * HDIM + gcol);
            float4 v;
            v.x = fmaxf(vv[0] + __expf(fmaf(sgv.x, zv.x, muv.x)), 0.0f);
            v.y = fmaxf(vv[1] + __expf(fmaf(sgv.y, zv.y, muv.y)), 0.0f);
            v.z = fmaxf(vv[2] + __expf(fmaf(sgv.z, zv.z, muv.z)), 0.0f);
            v.w = fmaxf(vv[3] + __expf(fmaf(sgv.w, zv.w, muv.w)), 0.0f);
            *reinterpret_cast<float4*>(
                out + (size_t)grow * OUTSTRIDE + outCol0 + gcol) = v;
            if constexpr (DO_ACT) {
                ushort4 av;
                av.x = f2bf(v.x); av.y = f2bf(v.y);
                av.z = f2bf(v.z); av.w = f2bf(v.w);
                *reinterpret_cast<ushort4*>(
                    actOut + (size_t)grow * HDIM + gcol) = av;
            }
        }
        LGKM0;   // half-h reads done before half-(h+1) overwrites
    }
}

// ---------------------------------------------------------------------------
extern "C" void kernel_launch(void* const* d_in, const int* in_sizes, int n_in,
                              void* d_out, int out_size, void* d_ws, size_t ws_size,
                              hipStream_t stream) {
    const float* x       = (const float*)d_in[0];
    const float* weights = (const float*)d_in[1];
    const float* masks   = (const float*)d_in[2];
    const float* mu      = (const float*)d_in[3];
    const float* sigma   = (const float*)d_in[4];
    const float* z       = (const float*)d_in[5];
    float* out = (float*)d_out;

    const size_t NELEM = (size_t)BDIM * HDIM;           // 16.78M
    unsigned short* actA = (unsigned short*)d_ws;
    unsigned short* actB = actA + NELEM;
    unsigned short* wbA  = actB + NELEM;
    unsigned short* wbB  = wbA + NELEM;                 // needs 128 MB total

    const bool fuse = ws_size >= 4 * NELEM * sizeof(unsigned short);
    const int CVT_BLOCKS = (int)(NELEM / 4) / 256;      // 16384 (fallback only)

    // one prep kernel: x->bf16 and W0*mask0->bf16
    prep_kernel<<<2048, 256, 0, stream>>>(x, weights, masks, actA, wbA);

    unsigned short* cur = actA;
    unsigned short* nxt = actB;
    unsigned short* wCur = wbA;
    unsigned short* wNxt = fuse ? wbB : wbA;

    dim3 grid(HDIM / 256, BDIM / 256);   // (16, 16) = 256 blocks = 1/CU

    for (int l = 0; l < LDIM; ++l) {
        if (!fuse && l > 0) {
            cvt_w_kernel<<<CVT_BLOCKS, 256, 0, stream>>>(
                weights + (size_t)l * NELEM, masks + (size_t)l * NELEM, wCur);
        }
        const bool doNext = fuse && (l + 1 < LDIM);
        const float* muL = mu + (size_t)l * HDIM;
        const float* sgL = sigma + (size_t)l * HDIM;
        const float* zL  = z + (size_t)l * NELEM;

        if (doNext) {
            gemm_layer<true, true><<<grid, 512, 0, stream>>>(
                cur, wCur, muL, sgL, zL, out, l * HDIM,
                nxt,
                weights + (size_t)(l + 1) * NELEM,
                masks + (size_t)(l + 1) * NELEM,
                wNxt);
        } else if (l + 1 < LDIM) {          // !fuse mid layers
            gemm_layer<false, true><<<grid, 512, 0, stream>>>(
                cur, wCur, muL, sgL, zL, out, l * HDIM,
                nxt, nullptr, nullptr, nullptr);
        } else {                             // last layer: no act, no cvt
            gemm_layer<false, false><<<grid, 512, 0, stream>>>(
                cur, wCur, muL, sgL, zL, out, l * HDIM,
                nullptr, nullptr, nullptr, nullptr);
        }

        unsigned short* tmp = cur; cur = nxt; nxt = tmp;
        if (fuse) { unsigned short* tw = wCur; wCur = wNxt; wNxt = tw; }
    }
}